// Round 2
// baseline (130.144 us; speedup 1.0000x reference)
//
#include <hip/hip_runtime.h>
#include <hip/hip_bf16.h>

// Problem constants (from reference)
#define Bg 64      // graphs
#define Nn 256     // nodes per subgraph
#define Ee 2048    // edges per subgraph
#define Dd 128     // hidden dim
#define Hh 4       // heads
#define MAXJ 96    // max incoming edges to node 0 tracked (mean ~9)

// Dual-dtype load: flag==1 -> fp32, flag==0 -> bf16
__device__ __forceinline__ float loadf(const void* p, long i, int f32) {
    if (f32) return ((const float*)p)[i];
    return __bfloat162float(((const __hip_bfloat16*)p)[i]);
}

// ---------------------------------------------------------------------------
// Kernel 0: detect float storage dtype. Read W1 as bf16; real bf16 weights
// are |x| < 0.3. If the data is actually fp32, the even halfwords are fp32
// low-mantissa bits whose bf16 exponent field is ~uniform -> |x|>64 or NaN
// with prob ~0.5 per element; over 256 elements detection is certain.
// ---------------------------------------------------------------------------
__global__ void detect_kernel(const void* W1, int* flag) {
    if (threadIdx.x == 0 && blockIdx.x == 0) {
        const __hip_bfloat16* p = (const __hip_bfloat16*)W1;
        int f = 0;
        for (int i = 0; i < 256; ++i) {
            float v = __bfloat162float(p[i]);
            if (!(v > -64.f && v < 64.f)) { f = 1; break; }  // NaN also lands here
        }
        *flag = f;
    }
}

// ---------------------------------------------------------------------------
// Kernel 1: fold attention vectors / mlp row through W.
//   wv[l][t][h][k] = sum_d att_t[h,d] * W_l[h*D+d, k]   (t: 0=src, 1=dst, 2=mlp)
//   bdot[l] = dot(bias_l, mlp_half_l) (+ mlp_b for l==0)
// grid: 6 blocks (l*3+t), 512 threads (tid = h*128 + k)
// ---------------------------------------------------------------------------
__global__ void precompute_kernel(
    const void* W1, const void* W2,
    const void* as1, const void* ad1,
    const void* as2, const void* ad2,
    const void* mlpw, const void* b1,
    const void* b2, const void* mlpb,
    const int* flag, float* wv, float* bdot)
{
    int f32 = *flag;
    int blk = blockIdx.x;
    int l = blk / 3, t = blk % 3;
    const void* W = l ? W2 : W1;
    const void* att;
    long abase = 0;
    if (t == 0)      att = l ? as2 : as1;
    else if (t == 1) att = l ? ad2 : ad1;
    else           { att = mlpw; abase = l * Dd; }   // mlp half for this layer

    int tid = threadIdx.x;           // 0..511
    int h = tid >> 7, k = tid & 127;

    float acc = 0.f;
    if (t == 2) {
        for (int d = 0; d < Dd; ++d)
            acc += loadf(att, abase + d, f32) *
                   loadf(W, (long)(h * Dd + d) * Dd + k, f32);
    } else {
        for (int d = 0; d < Dd; ++d)
            acc += loadf(att, (long)h * Dd + d, f32) *
                   loadf(W, (long)(h * Dd + d) * Dd + k, f32);
    }
    wv[blk * 512 + tid] = acc;

    if (t == 2) {
        __shared__ float s[Dd];
        const void* bias = l ? b2 : b1;
        if (tid < Dd)
            s[tid] = loadf(bias, tid, f32) * loadf(mlpw, l * Dd + tid, f32);
        __syncthreads();
        if (tid == 0) {
            float a = 0.f;
            for (int i = 0; i < Dd; ++i) a += s[i];
            if (l == 0) a += loadf(mlpb, 0, f32);
            bdot[l] = a;
        }
    }
}

// ---------------------------------------------------------------------------
// Kernel 2: per (graph, layer) — scalar contribution of the center node.
// grid: 128 blocks (b = x&63, l = x>>6), 256 threads.
// ---------------------------------------------------------------------------
__global__ void gat_center_kernel(
    const int* nn1, const int* nn2,
    const int* adj1, const int* adj2,
    const void* emb,
    const float* wv_all,   // [2][3][4][128]
    const float* bdot,     // [2]
    const int* flag,
    float* partial)        // [2][B]
{
    int f32 = *flag;
    int bx = blockIdx.x;
    int b = bx & (Bg - 1);
    int l = bx >> 6;
    const int* nodes = l ? nn2 : nn1;
    const int* adj   = l ? adj2 : adj1;
    const float* wv  = wv_all + l * (3 * Hh * Dd);

    __shared__ int   s_src[MAXJ];
    __shared__ int   s_gid[MAXJ];
    __shared__ int   s_cnt, s_jloop;
    __shared__ float s_rows[MAXJ * 132];       // +4 pad vs bank conflicts
    __shared__ float s_wv[3 * Hh * Dd];        // 1536 floats
    __shared__ float s_ps[MAXJ * Hh];
    __shared__ float s_pm[MAXJ * Hh];
    __shared__ float s_pd[Hh];
    __shared__ float s_hval[Hh];

    int tid = threadIdx.x;
    if (tid == 0) s_cnt = 0;
    __syncthreads();

    // Phase 1: find edges with dst == 0; stage fused weight vectors.
    const int* srcp = adj + b * 2 * Ee;
    const int* dstp = srcp + Ee;
    for (int e = tid; e < Ee; e += 256) {
        if (dstp[e] == 0) {
            int pos = atomicAdd(&s_cnt, 1);
            if (pos < MAXJ - 1) s_src[pos] = srcp[e];
        }
    }
    for (int i = tid; i < 3 * Hh * Dd; i += 256) s_wv[i] = wv[i];
    __syncthreads();

    if (tid == 0) {
        int c = s_cnt;
        if (c > MAXJ - 1) c = MAXJ - 1;
        s_src[c] = 0;        // self-loop (0 -> 0)
        s_jloop = c;
        s_cnt = c + 1;
    }
    __syncthreads();
    int cnt = s_cnt;

    // Phase 2: vocab ids, then stage embedding rows into LDS (fp32).
    if (tid < cnt) s_gid[tid] = nodes[b * Nn + s_src[tid]];
    __syncthreads();
    for (int idx = tid; idx < cnt * Dd; idx += 256) {
        int j = idx >> 7, k = idx & 127;
        s_rows[j * 132 + k] = loadf(emb, (long)s_gid[j] * Dd + k, f32);
    }
    __syncthreads();

    // Phase 3: dots. task = j*8 + h*2 + {0:ps,1:pm}; extra Hh tasks: pd.
    int ntask = cnt * 8 + Hh;
    for (int task = tid; task < ntask; task += 256) {
        int j, h, type;
        if (task < cnt * 8) {
            j = task >> 3;
            h = (task >> 1) & 3;
            type = (task & 1) ? 2 : 0;
        } else {
            j = s_jloop;
            h = task - cnt * 8;
            type = 1;
        }
        const float* wrow = s_wv + (type * Hh + h) * Dd;
        const float* row  = s_rows + j * 132;
        float acc = 0.f;
        #pragma unroll 8
        for (int k = 0; k < Dd; ++k) acc += row[k] * wrow[k];
        if (task < cnt * 8) {
            if (task & 1) s_pm[j * Hh + h] = acc;
            else          s_ps[j * Hh + h] = acc;
        } else {
            s_pd[h] = acc;
        }
    }
    __syncthreads();

    // Phase 4: per-head leaky-relu + softmax + weighted sum of pm.
    if (tid < Hh) {
        int h = tid;
        float pd = s_pd[h];
        float m = -1e30f;
        for (int j = 0; j < cnt; ++j) {
            float e = s_ps[j * Hh + h] + pd;
            e = (e >= 0.f) ? e : 0.2f * e;     // leaky relu, slope 0.2
            s_ps[j * Hh + h] = e;
            if (e > m) m = e;
        }
        float denom = 0.f, num = 0.f;
        for (int j = 0; j < cnt; ++j) {
            float ex = expf(s_ps[j * Hh + h] - m);
            denom += ex;
            num   += ex * s_pm[j * Hh + h];
        }
        s_hval[h] = num / denom;
    }
    __syncthreads();

    if (tid == 0) {
        float r = 0.25f * (s_hval[0] + s_hval[1] + s_hval[2] + s_hval[3])
                + bdot[l];
        partial[l * Bg + b] = r;
    }
}

// ---------------------------------------------------------------------------
// Kernel 3: combine two layer contributions -> output [B] (dtype per flag).
// ---------------------------------------------------------------------------
__global__ void combine_kernel(const float* partial, const int* flag, void* out)
{
    int b = threadIdx.x;
    if (b < Bg) {
        float v = partial[b] + partial[Bg + b];
        if (*flag) ((float*)out)[b] = v;
        else       ((__hip_bfloat16*)out)[b] = __float2bfloat16(v);
    }
}

extern "C" void kernel_launch(void* const* d_in, const int* in_sizes, int n_in,
                              void* d_out, int out_size, void* d_ws, size_t ws_size,
                              hipStream_t stream) {
    const int* nn1  = (const int*)d_in[0];
    const int* nn2  = (const int*)d_in[1];
    const int* adj1 = (const int*)d_in[2];
    const int* adj2 = (const int*)d_in[3];
    const void* emb  = d_in[4];
    const void* W1   = d_in[5];
    const void* as1  = d_in[6];
    const void* ad1  = d_in[7];
    const void* b1   = d_in[8];
    const void* W2   = d_in[9];
    const void* as2  = d_in[10];
    const void* ad2  = d_in[11];
    const void* b2   = d_in[12];
    const void* mlpw = d_in[13];
    const void* mlpb = d_in[14];

    float* ws_f    = (float*)d_ws;
    float* wv      = ws_f;            // 6*512 = 3072 floats
    float* bdot    = ws_f + 3072;     // 2 floats
    float* partial = ws_f + 3074;     // 128 floats
    int*   flag    = (int*)(ws_f + 3202);

    detect_kernel<<<1, 64, 0, stream>>>(W1, flag);

    precompute_kernel<<<6, 512, 0, stream>>>(
        W1, W2, as1, ad1, as2, ad2, mlpw, b1, b2, mlpb, flag, wv, bdot);

    gat_center_kernel<<<Bg * 2, 256, 0, stream>>>(
        nn1, nn2, adj1, adj2, emb, wv, bdot, flag, partial);

    combine_kernel<<<1, 64, 0, stream>>>(partial, flag, d_out);
}